// Round 1
// baseline (2938.091 us; speedup 1.0000x reference)
//
#include <hip/hip_runtime.h>

#define BATCH    1024
#define UNITS    1024
#define INSTEPS  64
#define OUTSTEPS 32
#define NF       4

typedef _Float16 half8 __attribute__((ext_vector_type(8)));
typedef float    f32x4 __attribute__((ext_vector_type(4)));

__device__ __forceinline__ float sigf(float x)  { return 1.0f / (1.0f + __expf(-x)); }
__device__ __forceinline__ float tanhf_(float x){ return 1.0f - 2.0f / (__expf(2.0f * x) + 1.0f); }

// One-time per launch: U fp32 [1024 k][4096 n] -> Ut f16 [4096 n][1024 k] (transposed)
__global__ void u_transpose(const float* __restrict__ U, _Float16* __restrict__ Ut) {
    __shared__ _Float16 T[64][72];   // pad 8 to break bank alignment
    const int tid = threadIdx.x;
    const int bid = blockIdx.x;            // 1024 blocks = 16 (k) x 64 (n)
    const int k0 = (bid >> 6) << 6;
    const int n0 = (bid & 63) << 6;
    #pragma unroll
    for (int i = 0; i < 16; ++i) {
        int q = i * 256 + tid;
        int r = q >> 6, cc = q & 63;       // coalesced along n
        T[r][cc] = (_Float16)U[(size_t)(k0 + r) * 4096 + n0 + cc];
    }
    __syncthreads();
    #pragma unroll
    for (int i = 0; i < 16; ++i) {
        int q = i * 256 + tid;
        int nn = q >> 6, kk = q & 63;      // coalesced along k
        Ut[(size_t)(n0 + nn) * 1024 + k0 + kk] = T[kk][nn];
    }
}

// One LSTM cell step, fused: z = xt@W + h@U + b ; gates ; c,h update ; optional pred=h@Wd+bd.
// Block tile: 128 rows x (4 gates x 16 units). Grid: 8 m-tiles x 64 unit-tiles = 512 blocks.
// 4 waves/block; wave = 32 rows x 64 cols (2x4 frags of 16x16, mfma_f32_16x16x32_f16).
__global__ __launch_bounds__(256, 2) void lstm_cell(
    const float* __restrict__ x, const float* __restrict__ W,
    const float* __restrict__ bias, const float* __restrict__ Wd,
    const float* __restrict__ bd, const _Float16* __restrict__ Ut,
    const _Float16* __restrict__ h_in, _Float16* __restrict__ h_out,
    float* __restrict__ cst, float* out,
    int t_in, int s_in, int s_out)
{
    // pad rows to 40 halves (80 B): 16B-aligned rows, conflict-free b128 frag reads
    __shared__ __align__(16) _Float16 As[128][40];
    __shared__ __align__(16) _Float16 Bs[64][40];
    __shared__ float xs[128][NF];

    const int tid = threadIdx.x;
    const int bid = blockIdx.x;
    const int m0     = (bid >> 6) << 7;                     // m-tile * 128
    const int u_tile = ((bid & 7) << 3) | ((bid >> 3) & 7); // XCD-band swizzle (bid%8 = XCD)
    const int u0     = u_tile << 4;                         // 16 units per block

    const int lane = tid & 63;
    const int wv   = tid >> 6;     // wave 0..3 -> rows wv*32..wv*32+31
    const int quad = lane >> 4;    // k-group within frag
    const int ln   = lane & 15;

    // ---- stage xt into LDS (fp32) ----
    #pragma unroll
    for (int i = 0; i < 2; ++i) {
        int q = i * 256 + tid;
        int r = q >> 2, f = q & 3;
        float v = (t_in >= 0)
                ? x[(size_t)(m0 + r) * (INSTEPS * NF) + t_in * NF + f]
                : out[(size_t)(m0 + r) * (OUTSTEPS * NF) + s_in * NF + f];
        xs[r][f] = v;
    }

    // ---- staging addresses (coalesced: 4 lanes x 16B = 64B per row) ----
    const int am  = tid >> 2;            // rows 0..63 (i=0) and +64 (i=1)
    const int akg = tid & 3;
    const _Float16* aptr0 = h_in + (size_t)(m0 + am) * UNITS + akg * 8;
    const _Float16* aptr1 = aptr0 + (size_t)64 * UNITS;
    const int bn  = tid >> 2;            // 0..63 : gate = bn>>4, unit = bn&15
    const int bkg = tid & 3;
    const int grow = ((bn >> 4) << 10) + u0 + (bn & 15);
    const _Float16* bptr = Ut + (size_t)grow * UNITS + bkg * 8;

    _Float16* awr0 = &As[am][akg * 8];
    _Float16* awr1 = &As[am + 64][akg * 8];
    _Float16* bwr  = &Bs[bn][bkg * 8];

    const _Float16* ard0 = &As[wv * 32 + ln][quad * 8];
    const _Float16* ard1 = &As[wv * 32 + 16 + ln][quad * 8];
    const _Float16* brd0 = &Bs[ln][quad * 8];
    const _Float16* brd1 = &Bs[16 + ln][quad * 8];
    const _Float16* brd2 = &Bs[32 + ln][quad * 8];
    const _Float16* brd3 = &Bs[48 + ln][quad * 8];

    float4 a0 = *(const float4*)aptr0;
    float4 a1 = *(const float4*)aptr1;
    float4 b0 = *(const float4*)bptr;

    f32x4 acc[2][4] = {};

    // ---- K loop: 32 chunks of BK=32 ----
    for (int kc = 0; kc < 32; ++kc) {
        __syncthreads();                    // prev chunk's frag reads done
        *(float4*)awr0 = a0;
        *(float4*)awr1 = a1;
        *(float4*)bwr  = b0;
        __syncthreads();                    // LDS visible
        if (kc < 31) {                      // prefetch next chunk (hidden under MFMA)
            int k1 = (kc + 1) * 32;
            a0 = *(const float4*)(aptr0 + k1);
            a1 = *(const float4*)(aptr1 + k1);
            b0 = *(const float4*)(bptr + k1);
        }
        half8 af0 = *(const half8*)ard0;
        half8 af1 = *(const half8*)ard1;
        half8 bf0 = *(const half8*)brd0;
        half8 bf1 = *(const half8*)brd1;
        half8 bf2 = *(const half8*)brd2;
        half8 bf3 = *(const half8*)brd3;
        acc[0][0] = __builtin_amdgcn_mfma_f32_16x16x32_f16(af0, bf0, acc[0][0], 0, 0, 0);
        acc[1][0] = __builtin_amdgcn_mfma_f32_16x16x32_f16(af1, bf0, acc[1][0], 0, 0, 0);
        acc[0][1] = __builtin_amdgcn_mfma_f32_16x16x32_f16(af0, bf1, acc[0][1], 0, 0, 0);
        acc[1][1] = __builtin_amdgcn_mfma_f32_16x16x32_f16(af1, bf1, acc[1][1], 0, 0, 0);
        acc[0][2] = __builtin_amdgcn_mfma_f32_16x16x32_f16(af0, bf2, acc[0][2], 0, 0, 0);
        acc[1][2] = __builtin_amdgcn_mfma_f32_16x16x32_f16(af1, bf2, acc[1][2], 0, 0, 0);
        acc[0][3] = __builtin_amdgcn_mfma_f32_16x16x32_f16(af0, bf3, acc[0][3], 0, 0, 0);
        acc[1][3] = __builtin_amdgcn_mfma_f32_16x16x32_f16(af1, bf3, acc[1][3], 0, 0, 0);
    }

    // ---- epilogue: + xt@W + b, gates, c/h update, fused pred ----
    float wt[4][4], bt[4];
    #pragma unroll
    for (int g = 0; g < 4; ++g) {
        int col = (g << 10) + u0 + ln;
        bt[g] = bias[col];
        #pragma unroll
        for (int f = 0; f < 4; ++f) wt[g][f] = W[f * 4096 + col];
    }
    float wd0 = 0, wd1 = 0, wd2 = 0, wd3 = 0, bd0 = 0, bd1 = 0, bd2 = 0, bd3 = 0;
    if (s_out >= 0) {
        const float* wdp = Wd + (size_t)(u0 + ln) * NF;
        wd0 = wdp[0]; wd1 = wdp[1]; wd2 = wdp[2]; wd3 = wdp[3];
        if (u_tile == 0) { bd0 = bd[0]; bd1 = bd[1]; bd2 = bd[2]; bd3 = bd[3]; }
    }

    #pragma unroll
    for (int r = 0; r < 2; ++r) {
        #pragma unroll
        for (int i = 0; i < 4; ++i) {
            int rl = wv * 32 + r * 16 + quad * 4 + i;   // C/D: row=quad*4+reg, col=ln
            int R  = m0 + rl;
            float x0 = xs[rl][0], x1 = xs[rl][1], x2 = xs[rl][2], x3 = xs[rl][3];
            float zi = acc[r][0][i] + bt[0] + x0*wt[0][0] + x1*wt[0][1] + x2*wt[0][2] + x3*wt[0][3];
            float zf = acc[r][1][i] + bt[1] + x0*wt[1][0] + x1*wt[1][1] + x2*wt[1][2] + x3*wt[1][3];
            float zg = acc[r][2][i] + bt[2] + x0*wt[2][0] + x1*wt[2][1] + x2*wt[2][2] + x3*wt[2][3];
            float zo = acc[r][3][i] + bt[3] + x0*wt[3][0] + x1*wt[3][1] + x2*wt[3][2] + x3*wt[3][3];
            size_t ci = (size_t)R * UNITS + u0 + ln;
            float cold = cst[ci];
            float si = sigf(zi), sf = sigf(zf), so = sigf(zo);
            float cn = sf * cold + si * tanhf_(zg);
            float hn = so * tanhf_(cn);
            cst[ci] = cn;
            h_out[ci] = (_Float16)hn;
            if (s_out >= 0) {
                float p0 = hn * wd0, p1 = hn * wd1, p2 = hn * wd2, p3 = hn * wd3;
                #pragma unroll
                for (int mk = 1; mk < 16; mk <<= 1) {   // reduce over 16 units (in-quad)
                    p0 += __shfl_xor(p0, mk);
                    p1 += __shfl_xor(p1, mk);
                    p2 += __shfl_xor(p2, mk);
                    p3 += __shfl_xor(p3, mk);
                }
                if (ln == 0) {
                    float* op = out + (size_t)R * (OUTSTEPS * NF) + s_out * NF;
                    atomicAdd(op + 0, p0 + bd0);
                    atomicAdd(op + 1, p1 + bd1);
                    atomicAdd(op + 2, p2 + bd2);
                    atomicAdd(op + 3, p3 + bd3);
                }
            }
        }
    }
}

extern "C" void kernel_launch(void* const* d_in, const int* in_sizes, int n_in,
                              void* d_out, int out_size, void* d_ws, size_t ws_size,
                              hipStream_t stream) {
    (void)in_sizes; (void)n_in; (void)ws_size;
    const float* x  = (const float*)d_in[0];
    const float* W  = (const float*)d_in[1];
    const float* U  = (const float*)d_in[2];
    const float* b  = (const float*)d_in[3];
    const float* Wd = (const float*)d_in[4];
    const float* bd = (const float*)d_in[5];
    float* out = (float*)d_out;

    char* ws = (char*)d_ws;
    float*    cst = (float*)ws;                       // 4 MB  c state fp32
    _Float16* hA  = (_Float16*)(ws + (4 << 20));      // 2 MB  h ping
    _Float16* hB  = (_Float16*)(ws + (6 << 20));      // 2 MB  h pong
    _Float16* Ut  = (_Float16*)(ws + (8 << 20));      // 8 MB  U^T f16

    hipMemsetAsync(ws, 0, 6 << 20, stream);                       // zero c + hA
    hipMemsetAsync(d_out, 0, (size_t)out_size * sizeof(float), stream); // preds accumulate
    u_transpose<<<1024, 256, 0, stream>>>(U, Ut);

    _Float16* hin = hA; _Float16* hout = hB;
    for (int t = 0; t < INSTEPS; ++t) {               // warmup; last step emits pred0
        int so = (t == INSTEPS - 1) ? 0 : -1;
        lstm_cell<<<512, 256, 0, stream>>>(x, W, b, Wd, bd, Ut, hin, hout, cst, out, t, -1, so);
        _Float16* tmp = hin; hin = hout; hout = tmp;
    }
    for (int s = 1; s < OUTSTEPS; ++s) {              // autoregressive decode
        lstm_cell<<<512, 256, 0, stream>>>(x, W, b, Wd, bd, Ut, hin, hout, cst, out, -1, s - 1, s);
        _Float16* tmp = hin; hin = hout; hout = tmp;
    }
}